// Round 3
// baseline (4598.071 us; speedup 1.0000x reference)
//
#include <hip/hip_runtime.h>

// ---- problem constants (match reference) ----
constexpr int N_ATOMS  = 100000;
constexpr int NATOMS1  = 100001;   // includes padding row 0
constexpr int NBONDS1  = 200001;
constexpr int MAXNB    = 6;
constexpr int AF       = 133;      // ATOM_FDIM
constexpr int BF       = 147;      // BOND_FDIM
constexpr int H        = 300;      // HIDDEN
constexpr int NMOL     = 2048;
constexpr int QH       = H / 4;    // 75 groups of 4 bf16 (8B) per row

typedef unsigned short u16;
typedef unsigned int   u32;

__device__ inline float b2f(u16 h) {
    union { u32 u; float f; } x; x.u = ((u32)h) << 16; return x.f;
}
__device__ inline u16 f2b(float f) {
    union { float f; u32 u; } x; x.f = f;
    u32 r = (x.u + 0x7FFFu + ((x.u >> 16) & 1u)) >> 16;
    return (u16)r;
}

// ---- tiled fp32 GEMM with bf16 concat input / bf16 output ----
// C[M x 300] = relu( concat(A1_fp32[M x KA], A2_bf16[M x (K-KA)]) @ W + bias? )
// W row kk: kk < KW -> W1[kk], else W2[kk-KW]   (fold [W_i; W_h])
#define BM 64
#define BN 64
#define BK 16

template<int K, int KA, int KW, bool HAS_A2, bool HAS_W2, bool HAS_BIAS>
__global__ __launch_bounds__(256)
void gemm_k(const float* __restrict__ A1, int lda1,
            const u16* __restrict__ A2,            // stride H, cols KA..K-1
            const float* __restrict__ W1,          // rows 0..KW-1, stride H
            const float* __restrict__ W2,          // rows KW..K-1, stride H
            const float* __restrict__ bias,
            u16* __restrict__ out, int M)
{
    __shared__ float As[BK][BM + 4];
    __shared__ float Ws[BK][BN + 4];

    const int tid  = threadIdx.x;
    const int tx   = tid & 15;
    const int ty   = tid >> 4;
    const int row0 = blockIdx.y * BM;
    const int col0 = blockIdx.x * BN;

    float acc[4][4] = {};

    for (int k0 = 0; k0 < K; k0 += BK) {
        // A tile: As[k][m]; consecutive tid -> consecutive kk
        #pragma unroll
        for (int i = 0; i < 4; ++i) {
            int lin = tid + 256 * i;
            int k   = lin & 15;
            int m   = lin >> 4;
            int r   = row0 + m;
            int kk  = k0 + k;
            float v = 0.f;
            if (r < M && kk < K) {
                if (!HAS_A2 || kk < KA) v = A1[(long)r * lda1 + kk];
                else                    v = b2f(A2[(long)r * H + (kk - KA)]);
            }
            As[k][m] = v;
        }
        // W tile: Ws[k][n]; consecutive tid -> consecutive col (coalesced)
        #pragma unroll
        for (int i = 0; i < 4; ++i) {
            int lin = tid + 256 * i;
            int n   = lin & 63;
            int k   = lin >> 6;
            int kk  = k0 + k;
            int c   = col0 + n;
            float v = 0.f;
            if (kk < K && c < H) {
                if (!HAS_W2 || kk < KW) v = W1[kk * H + c];
                else                    v = W2[(kk - KW) * H + c];
            }
            Ws[k][n] = v;
        }
        __syncthreads();

        #pragma unroll
        for (int k = 0; k < BK; ++k) {
            float4 a = *(const float4*)&As[k][ty * 4];
            float4 w = *(const float4*)&Ws[k][tx * 4];
            float av[4] = {a.x, a.y, a.z, a.w};
            float wv[4] = {w.x, w.y, w.z, w.w};
            #pragma unroll
            for (int i = 0; i < 4; ++i)
                #pragma unroll
                for (int j = 0; j < 4; ++j)
                    acc[i][j] += av[i] * wv[j];
        }
        __syncthreads();
    }

    const int c = col0 + tx * 4;
    if (c >= H) return;     // H % 4 == 0: whole group in/out together
    #pragma unroll
    for (int i = 0; i < 4; ++i) {
        int r = row0 + ty * 4 + i;
        if (r >= M) continue;
        float v0 = acc[i][0], v1 = acc[i][1], v2 = acc[i][2], v3 = acc[i][3];
        if constexpr (HAS_BIAS) {
            v0 += bias[c]; v1 += bias[c + 1]; v2 += bias[c + 2]; v3 += bias[c + 3];
        }
        v0 = fmaxf(v0, 0.f); v1 = fmaxf(v1, 0.f);
        v2 = fmaxf(v2, 0.f); v3 = fmaxf(v3, 0.f);
        uint2 o;
        o.x = (u32)f2b(v0) | ((u32)f2b(v1) << 16);
        o.y = (u32)f2b(v2) | ((u32)f2b(v3) << 16);
        *(uint2*)(out + (long)r * H + c) = o;   // r*600 + c*2 bytes, 8B aligned
    }
}

// a_msg[a] = sum_j P[a2b[a][j]]   (bf16 in/out, fp32 accumulate)
__global__ __launch_bounds__(256)
void atom_sum_k(const u16* __restrict__ P, const int* __restrict__ a2b,
                u16* __restrict__ amsg)
{
    int idx = blockIdx.x * 256 + threadIdx.x;
    if (idx >= NATOMS1 * QH) return;
    int a = idx / QH, q = idx - a * QH;
    const int* nb = a2b + a * MAXNB;
    float s0 = 0.f, s1 = 0.f, s2 = 0.f, s3 = 0.f;
    #pragma unroll
    for (int j = 0; j < MAXNB; ++j) {
        int b = nb[j];
        uint2 v = *(const uint2*)(P + (long)b * H + q * 4);
        s0 += b2f((u16)(v.x & 0xFFFF)); s1 += b2f((u16)(v.x >> 16));
        s2 += b2f((u16)(v.y & 0xFFFF)); s3 += b2f((u16)(v.y >> 16));
    }
    uint2 o;
    o.x = (u32)f2b(s0) | ((u32)f2b(s1) << 16);
    o.y = (u32)f2b(s2) | ((u32)f2b(s3) << 16);
    *(uint2*)(amsg + (long)a * H + q * 4) = o;
}

// Q[b] = a_msg[b2a[b]] - P[b2revb[b]]
__global__ __launch_bounds__(256)
void bond_update_k(const u16* __restrict__ amsg, const u16* __restrict__ P,
                   const int* __restrict__ b2a, const int* __restrict__ b2revb,
                   u16* __restrict__ Q)
{
    int idx = blockIdx.x * 256 + threadIdx.x;
    if (idx >= NBONDS1 * QH) return;
    int b = idx / QH, q = idx - b * QH;
    int a  = b2a[b];
    int rb = b2revb[b];
    uint2 x = *(const uint2*)(amsg + (long)a * H + q * 4);
    uint2 y = *(const uint2*)(P + (long)rb * H + q * 4);
    float v0 = b2f((u16)(x.x & 0xFFFF)) - b2f((u16)(y.x & 0xFFFF));
    float v1 = b2f((u16)(x.x >> 16))    - b2f((u16)(y.x >> 16));
    float v2 = b2f((u16)(x.y & 0xFFFF)) - b2f((u16)(y.y & 0xFFFF));
    float v3 = b2f((u16)(x.y >> 16))    - b2f((u16)(y.y >> 16));
    uint2 o;
    o.x = (u32)f2b(v0) | ((u32)f2b(v1) << 16);
    o.y = (u32)f2b(v2) | ((u32)f2b(v3) << 16);
    *(uint2*)(Q + (long)b * H + q * 4) = o;
}

__global__ __launch_bounds__(256)
void counts_k(const int* __restrict__ mol_ids, float* __restrict__ cnt)
{
    int i = blockIdx.x * 256 + threadIdx.x;
    if (i < N_ATOMS) atomicAdd(&cnt[mol_ids[i]], 1.0f);
}

// scatter atom_hiddens[1:] (bf16) into mol sums (fp32 atomics)
__global__ __launch_bounds__(256)
void scatter_k(const u16* __restrict__ ah, const int* __restrict__ mol_ids,
               float* __restrict__ out)
{
    int idx = blockIdx.x * 256 + threadIdx.x;
    if (idx >= N_ATOMS * QH) return;
    int i = idx / QH, q = idx - i * QH;
    uint2 v = *(const uint2*)(ah + (long)(i + 1) * H + q * 4);
    int m = mol_ids[i];
    float* o = &out[(long)m * H + q * 4];
    atomicAdd(o + 0, b2f((u16)(v.x & 0xFFFF)));
    atomicAdd(o + 1, b2f((u16)(v.x >> 16)));
    atomicAdd(o + 2, b2f((u16)(v.y & 0xFFFF)));
    atomicAdd(o + 3, b2f((u16)(v.y >> 16)));
}

__global__ __launch_bounds__(256)
void divide_k(float* __restrict__ out, const float* __restrict__ cnt)
{
    int idx = blockIdx.x * 256 + threadIdx.x;
    if (idx >= NMOL * H) return;
    out[idx] /= fmaxf(cnt[idx / H], 1.0f);
}

extern "C" void kernel_launch(void* const* d_in, const int* in_sizes, int n_in,
                              void* d_out, int out_size, void* d_ws, size_t ws_size,
                              hipStream_t stream)
{
    const float* f_atoms = (const float*)d_in[0];
    const float* f_bonds = (const float*)d_in[1];
    const float* W_i     = (const float*)d_in[2];
    const float* W_h     = (const float*)d_in[3];
    const float* W_o     = (const float*)d_in[4];
    const float* b_o     = (const float*)d_in[5];
    const int*   a2b     = (const int*)d_in[6];
    const int*   b2a     = (const int*)d_in[7];
    const int*   b2revb  = (const int*)d_in[8];
    const int*   mol_ids = (const int*)d_in[9];
    float* out = (float*)d_out;

    char* ws = (char*)d_ws;
    size_t off = 0;
    auto alloc = [&](size_t bytes) -> void* {
        void* p = ws + off;
        off += (bytes + 255) & ~(size_t)255;
        return p;
    };
    u16*   P     = (u16*)alloc(sizeof(u16) * (size_t)NBONDS1 * H);   // 120 MB
    u16*   Q     = (u16*)alloc(sizeof(u16) * (size_t)NBONDS1 * H);   // 120 MB (also atom_hiddens)
    u16*   a_msg = (u16*)alloc(sizeof(u16) * (size_t)NATOMS1 * H);   // 60 MB
    float* cnt   = (float*)alloc(sizeof(float) * NMOL);
    const size_t needed = off;   // ~300.01 MB

    if (ws_size < needed) {
        // Diagnostic: not enough scratch -> leave out as zeros (absmax will be
        // exactly the stub signature 28.625, distinguishing this from a crash).
        hipMemsetAsync(d_out, 0, sizeof(float) * (size_t)NMOL * H, stream);
        return;
    }

    hipMemsetAsync(d_out, 0, sizeof(float) * (size_t)NMOL * H, stream);
    hipMemsetAsync(cnt, 0, sizeof(float) * NMOL, stream);

    const dim3 blk(256);
    const dim3 gB(5, (NBONDS1 + BM - 1) / BM);   // 5 x 3126
    const dim3 gA(5, (NATOMS1 + BM - 1) / BM);   // 5 x 1563
    const int gAS = (NATOMS1 * QH + 255) / 256;
    const int gBU = (NBONDS1 * QH + 255) / 256;

    // P = relu(f_bonds @ W_i)
    gemm_k<BF, BF, BF, false, false, false><<<gB, blk, 0, stream>>>(
        f_bonds, BF, nullptr, W_i, nullptr, nullptr, P, NBONDS1);

    for (int d = 0; d < 2; ++d) {
        atom_sum_k<<<gAS, blk, 0, stream>>>(P, a2b, a_msg);
        bond_update_k<<<gBU, blk, 0, stream>>>(a_msg, P, b2a, b2revb, Q);
        // P = relu( f_bonds @ W_i + Q @ W_h )   (b_input recomputed via fold)
        gemm_k<BF + H, BF, BF, true, true, false><<<gB, blk, 0, stream>>>(
            f_bonds, BF, Q, W_i, W_h, nullptr, P, NBONDS1);
    }
    atom_sum_k<<<gAS, blk, 0, stream>>>(P, a2b, a_msg);

    // atom_hiddens = relu(concat(f_atoms, a_msg) @ W_o + b_o)  -> reuse Q
    gemm_k<AF + H, AF, AF + H, true, false, true><<<gA, blk, 0, stream>>>(
        f_atoms, AF, a_msg, W_o, nullptr, b_o, Q, NATOMS1);

    counts_k<<<(N_ATOMS + 255) / 256, blk, 0, stream>>>(mol_ids, cnt);
    scatter_k<<<(N_ATOMS * QH + 255) / 256, blk, 0, stream>>>(Q, mol_ids, out);
    divide_k<<<(NMOL * H + 255) / 256, blk, 0, stream>>>(out, cnt);
}

// Round 4
// 1946.258 us; speedup vs baseline: 2.3625x; 2.3625x over previous
//
#include <hip/hip_runtime.h>

// ---- problem constants ----
constexpr int N_ATOMS = 100000;
constexpr int NATOMS1 = 100001;
constexpr int NBONDS1 = 200001;
constexpr int MAXNB   = 6;
constexpr int AF      = 133;    // ATOM_FDIM
constexpr int BF      = 147;    // BOND_FDIM
constexpr int H       = 300;    // HIDDEN
constexpr int NMOL    = 2048;
constexpr int KP      = 448;    // padded K for both GEMM families
constexpr int NP      = 320;    // padded N (20 frags of 16)
constexpr int QCOL_B  = 148;    // Q (bond msg) column offset in AB  (8B-aligned: 148*2=296)
constexpr int QCOL_A  = 136;    // a_msg column offset in AA        (136*2=272, 8B-aligned)
constexpr int QH      = 75;     // 300/4 groups per row

typedef unsigned short u16;
typedef unsigned int   u32;
typedef __attribute__((ext_vector_type(8))) short bh8;   // 8 bf16 = 4 VGPRs
typedef __attribute__((ext_vector_type(4))) float f32x4;

__device__ inline float b2f(u16 h) {
    union { u32 u; float f; } x; x.u = ((u32)h) << 16; return x.f;
}
__device__ inline u16 f2b(float f) {
    union { float f; u32 u; } x; x.f = f;
    return (u16)((x.u + 0x7FFFu + ((x.u >> 16) & 1u)) >> 16);
}

// =====================  MFMA GEMM  =====================
// out[M x 300] = relu( A[M x 448](bf16) @ Wt^T + bias? )
// Wt is [320 x 448] bf16 (column c of W stored as row c), zero-padded.
// Block: 256 thr = 4 waves; tile 64 rows x 320 cols (wave w: cols 80w..80w+79).
// LDS fragment-order: frag(fm/cf, ks) read = base + lane*16 (conflict-free).
template<bool HAS_BIAS>
__global__ __launch_bounds__(256, 2)
void mfma_gemm_k(const u16* __restrict__ A, const u16* __restrict__ Wt,
                 const float* __restrict__ bias, u16* __restrict__ out, int M)
{
    __shared__ __align__(16) unsigned char smem[48 * 1024];  // A: 8KB, B: 40KB
    const int tid  = threadIdx.x;
    const int lane = tid & 63;
    const int w    = tid >> 6;
    const int row0 = blockIdx.x * 64;

    f32x4 acc[4][5];
    #pragma unroll
    for (int i = 0; i < 4; ++i)
        #pragma unroll
        for (int j = 0; j < 5; ++j)
            acc[i][j] = (f32x4)0.f;

    for (int kt = 0; kt < KP / 64; ++kt) {
        const int k0 = kt * 64;
        // ---- stage A tile (64 x 64 bf16 = 8KB), fragment order ----
        #pragma unroll
        for (int i = 0; i < 2; ++i) {
            int cid = tid + 256 * i;
            int r   = cid & 63;
            int kk  = cid >> 6;           // 0..7 (8 bf16 chunks)
            int ks  = kk >> 2, sub = kk & 3;
            uint4 v = {0u, 0u, 0u, 0u};
            int row = row0 + r;
            if (row < M) v = *(const uint4*)(A + (size_t)row * KP + k0 + kk * 8);
            *(uint4*)(smem + (((r >> 4) * 2 + ks) * 1024) + sub * 256 + (r & 15) * 16) = v;
        }
        // ---- stage B tile (320 cols x 64 k = 40KB), fragment order ----
        #pragma unroll
        for (int i = 0; i < 10; ++i) {
            int cid = tid + 256 * i;      // 0..2559
            int kk  = cid / 320;
            int col = cid - kk * 320;
            int ks  = kk >> 2, sub = kk & 3;
            uint4 v = *(const uint4*)(Wt + (size_t)col * KP + k0 + kk * 8);
            *(uint4*)(smem + 8192 + (((col >> 4) * 2 + ks) * 1024) + sub * 256 + (col & 15) * 16) = v;
        }
        __syncthreads();
        #pragma unroll
        for (int ks = 0; ks < 2; ++ks) {
            bh8 af[4], bf_[5];
            #pragma unroll
            for (int fm = 0; fm < 4; ++fm)
                af[fm] = *(const bh8*)(smem + (fm * 2 + ks) * 1024 + lane * 16);
            #pragma unroll
            for (int cf = 0; cf < 5; ++cf)
                bf_[cf] = *(const bh8*)(smem + 8192 + ((w * 5 + cf) * 2 + ks) * 1024 + lane * 16);
            #pragma unroll
            for (int fm = 0; fm < 4; ++fm)
                #pragma unroll
                for (int cf = 0; cf < 5; ++cf)
                    acc[fm][cf] = __builtin_amdgcn_mfma_f32_16x16x32_bf16(
                        af[fm], bf_[cf], acc[fm][cf], 0, 0, 0);
        }
        __syncthreads();
    }

    // epilogue: D row = (lane>>4)*4 + i (+16*fm), col = lane&15 (+16*cf +80*w)
    const int r4  = (lane >> 4) * 4;
    const int c15 = lane & 15;
    #pragma unroll
    for (int cf = 0; cf < 5; ++cf) {
        int col = w * 80 + cf * 16 + c15;
        if (col >= H) continue;
        float bv = HAS_BIAS ? bias[col] : 0.f;
        #pragma unroll
        for (int fm = 0; fm < 4; ++fm) {
            #pragma unroll
            for (int i = 0; i < 4; ++i) {
                int row = row0 + fm * 16 + r4 + i;
                if (row < M)
                    out[(size_t)row * H + col] = f2b(fmaxf(acc[fm][cf][i] + bv, 0.f));
            }
        }
    }
}

// =====================  prep kernels  =====================
// Wtih[c][k]: k<147 -> W_i[k][c]; k>=148 -> W_h[k-148][c]; else 0.  (c<300)
// Wto [c][k]: k<133 -> W_o[k][c]; 136<=k<436 -> W_o[133+k-136][c]; else 0.
__global__ __launch_bounds__(256)
void prep_w_k(const float* __restrict__ Wi, const float* __restrict__ Wh,
              const float* __restrict__ Wo, u16* __restrict__ Wtih, u16* __restrict__ Wto)
{
    int c = blockIdx.x;              // 0..319
    for (int k = threadIdx.x; k < KP; k += 256) {
        u16 v1 = 0, v2 = 0;
        if (c < H) {
            if (k < BF)              v1 = f2b(Wi[k * H + c]);
            else if (k >= QCOL_B)    v1 = f2b(Wh[(k - QCOL_B) * H + c]);
            if (k < AF)              v2 = f2b(Wo[k * H + c]);
            else if (k >= QCOL_A && k < QCOL_A + H)
                                     v2 = f2b(Wo[(AF + k - QCOL_A) * H + c]);
        }
        Wtih[c * KP + k] = v1;
        Wto[c * KP + k]  = v2;
    }
}

// AB[b][0:147] = bf16(f_bonds[b]); rest of row = 0 (Q region zero => GEMM1 fold works)
__global__ __launch_bounds__(256)
void prep_bonds_k(const float* __restrict__ fb, u16* __restrict__ AB)
{
    int idx = blockIdx.x * 256 + threadIdx.x;   // over NBONDS1 * 112 groups
    if (idx >= NBONDS1 * (KP / 4)) return;
    int b = idx / (KP / 4), g = idx - b * (KP / 4);
    int c0 = g * 4;
    u16 o[4];
    #pragma unroll
    for (int j = 0; j < 4; ++j) {
        int c = c0 + j;
        o[j] = (c < BF) ? f2b(fb[(size_t)b * BF + c]) : (u16)0;
    }
    uint2 p;
    p.x = (u32)o[0] | ((u32)o[1] << 16);
    p.y = (u32)o[2] | ((u32)o[3] << 16);
    *(uint2*)(AB + (size_t)b * KP + c0) = p;
}

// AA head (cols 0..135: f_atoms then 0) and tail (cols 436..447: 0)
__global__ __launch_bounds__(256)
void prep_atoms_k(const float* __restrict__ fa, u16* __restrict__ AA)
{
    int idx = blockIdx.x * 256 + threadIdx.x;   // NATOMS1 * 37 groups
    if (idx >= NATOMS1 * 37) return;
    int a = idx / 37, g = idx - a * 37;
    int c0 = (g < 34) ? g * 4 : 436 + (g - 34) * 4;
    u16 o[4];
    #pragma unroll
    for (int j = 0; j < 4; ++j) {
        int c = c0 + j;
        o[j] = (c < AF) ? f2b(fa[(size_t)a * AF + c]) : (u16)0;
    }
    uint2 p;
    p.x = (u32)o[0] | ((u32)o[1] << 16);
    p.y = (u32)o[2] | ((u32)o[3] << 16);
    *(uint2*)(AA + (size_t)a * KP + c0) = p;
}

// =====================  gather kernels  =====================
// AA[a][136+4q .. ] = sum_j P[a2b[a][j]][4q ..]
__global__ __launch_bounds__(256)
void atom_sum_k(const u16* __restrict__ P, const int* __restrict__ a2b,
                u16* __restrict__ AA)
{
    int idx = blockIdx.x * 256 + threadIdx.x;
    if (idx >= NATOMS1 * QH) return;
    int a = idx / QH, q = idx - a * QH;
    const int* nb = a2b + a * MAXNB;
    float s0 = 0.f, s1 = 0.f, s2 = 0.f, s3 = 0.f;
    #pragma unroll
    for (int j = 0; j < MAXNB; ++j) {
        int b = nb[j];
        uint2 v = *(const uint2*)(P + (size_t)b * H + q * 4);
        s0 += b2f((u16)(v.x & 0xFFFF)); s1 += b2f((u16)(v.x >> 16));
        s2 += b2f((u16)(v.y & 0xFFFF)); s3 += b2f((u16)(v.y >> 16));
    }
    uint2 o;
    o.x = (u32)f2b(s0) | ((u32)f2b(s1) << 16);
    o.y = (u32)f2b(s2) | ((u32)f2b(s3) << 16);
    *(uint2*)(AA + (size_t)a * KP + QCOL_A + q * 4) = o;
}

// AB[b][148+4q ..] = AA[b2a[b]][136+4q ..] - P[b2revb[b]][4q ..]
__global__ __launch_bounds__(256)
void bond_update_k(const u16* __restrict__ AA, const u16* __restrict__ P,
                   const int* __restrict__ b2a, const int* __restrict__ b2revb,
                   u16* __restrict__ AB)
{
    int idx = blockIdx.x * 256 + threadIdx.x;
    if (idx >= NBONDS1 * QH) return;
    int b = idx / QH, q = idx - b * QH;
    int a  = b2a[b];
    int rb = b2revb[b];
    uint2 x = *(const uint2*)(AA + (size_t)a * KP + QCOL_A + q * 4);
    uint2 y = *(const uint2*)(P + (size_t)rb * H + q * 4);
    float v0 = b2f((u16)(x.x & 0xFFFF)) - b2f((u16)(y.x & 0xFFFF));
    float v1 = b2f((u16)(x.x >> 16))    - b2f((u16)(y.x >> 16));
    float v2 = b2f((u16)(x.y & 0xFFFF)) - b2f((u16)(y.y & 0xFFFF));
    float v3 = b2f((u16)(x.y >> 16))    - b2f((u16)(y.y >> 16));
    uint2 o;
    o.x = (u32)f2b(v0) | ((u32)f2b(v1) << 16);
    o.y = (u32)f2b(v2) | ((u32)f2b(v3) << 16);
    *(uint2*)(AB + (size_t)b * KP + QCOL_B + q * 4) = o;
}

// =====================  pooling  =====================
__global__ __launch_bounds__(256)
void counts_k(const int* __restrict__ mol_ids, float* __restrict__ cnt)
{
    int i = blockIdx.x * 256 + threadIdx.x;
    if (i < N_ATOMS) atomicAdd(&cnt[mol_ids[i]], 1.0f);
}

__global__ __launch_bounds__(256)
void scatter_k(const u16* __restrict__ ah, const int* __restrict__ mol_ids,
               float* __restrict__ out)
{
    int idx = blockIdx.x * 256 + threadIdx.x;
    if (idx >= N_ATOMS * QH) return;
    int i = idx / QH, q = idx - i * QH;
    uint2 v = *(const uint2*)(ah + (size_t)(i + 1) * H + q * 4);
    int m = mol_ids[i];
    float* o = &out[(size_t)m * H + q * 4];
    atomicAdd(o + 0, b2f((u16)(v.x & 0xFFFF)));
    atomicAdd(o + 1, b2f((u16)(v.x >> 16)));
    atomicAdd(o + 2, b2f((u16)(v.y & 0xFFFF)));
    atomicAdd(o + 3, b2f((u16)(v.y >> 16)));
}

__global__ __launch_bounds__(256)
void divide_k(float* __restrict__ out, const float* __restrict__ cnt)
{
    int idx = blockIdx.x * 256 + threadIdx.x;
    if (idx >= NMOL * H) return;
    out[idx] /= fmaxf(cnt[idx / H], 1.0f);
}

// =====================  driver  =====================
extern "C" void kernel_launch(void* const* d_in, const int* in_sizes, int n_in,
                              void* d_out, int out_size, void* d_ws, size_t ws_size,
                              hipStream_t stream)
{
    const float* f_atoms = (const float*)d_in[0];
    const float* f_bonds = (const float*)d_in[1];
    const float* W_i     = (const float*)d_in[2];
    const float* W_h     = (const float*)d_in[3];
    const float* W_o     = (const float*)d_in[4];
    const float* b_o     = (const float*)d_in[5];
    const int*   a2b     = (const int*)d_in[6];
    const int*   b2a     = (const int*)d_in[7];
    const int*   b2revb  = (const int*)d_in[8];
    const int*   mol_ids = (const int*)d_in[9];
    float* out = (float*)d_out;

    char* ws = (char*)d_ws;
    size_t off = 0;
    auto alloc = [&](size_t bytes) -> void* {
        void* p = ws + off;
        off += (bytes + 255) & ~(size_t)255;
        return p;
    };
    u16* AB   = (u16*)alloc(sizeof(u16) * (size_t)NBONDS1 * KP);  // 179.2 MB
    u16* AA   = (u16*)alloc(sizeof(u16) * (size_t)NATOMS1 * KP);  //  89.6 MB
    u16* P    = (u16*)alloc(sizeof(u16) * (size_t)NBONDS1 * H);   // 120.0 MB (bond msgs; reused as atom_hiddens)
    u16* Wtih = (u16*)alloc(sizeof(u16) * (size_t)NP * KP);       // 287 KB
    u16* Wto  = (u16*)alloc(sizeof(u16) * (size_t)NP * KP);       // 287 KB
    float* cnt = (float*)alloc(sizeof(float) * NMOL);
    const size_t needed = off;                                    // ~389.4 MB

    if (ws_size < needed) {
        // Diagnostic: absmax will be exactly 28.625 (zeros) => ws too small.
        hipMemsetAsync(d_out, 0, sizeof(float) * (size_t)NMOL * H, stream);
        return;
    }

    hipMemsetAsync(d_out, 0, sizeof(float) * (size_t)NMOL * H, stream);
    hipMemsetAsync(cnt, 0, sizeof(float) * NMOL, stream);

    const dim3 blk(256);
    const int gB  = (NBONDS1 + 63) / 64;                 // 3126
    const int gA  = (NATOMS1 + 63) / 64;                 // 1563
    const int gAS = (NATOMS1 * QH + 255) / 256;
    const int gBU = (NBONDS1 * QH + 255) / 256;

    prep_w_k<<<NP, blk, 0, stream>>>(W_i, W_h, W_o, Wtih, Wto);
    prep_bonds_k<<<(NBONDS1 * (KP / 4) + 255) / 256, blk, 0, stream>>>(f_bonds, AB);
    prep_atoms_k<<<(NATOMS1 * 37 + 255) / 256, blk, 0, stream>>>(f_atoms, AA);

    // layer 1: Q region of AB is zero -> AB@[Wi;Wh] == f_bonds@W_i
    mfma_gemm_k<false><<<gB, blk, 0, stream>>>(AB, Wtih, nullptr, P, NBONDS1);

    for (int d = 0; d < 2; ++d) {
        atom_sum_k<<<gAS, blk, 0, stream>>>(P, a2b, AA);
        bond_update_k<<<gBU, blk, 0, stream>>>(AA, P, b2a, b2revb, AB);
        mfma_gemm_k<false><<<gB, blk, 0, stream>>>(AB, Wtih, nullptr, P, NBONDS1);
    }
    atom_sum_k<<<gAS, blk, 0, stream>>>(P, a2b, AA);

    // atom layer: reuse P as atom_hiddens
    mfma_gemm_k<true><<<gA, blk, 0, stream>>>(AA, Wto, b_o, P, NATOMS1);

    counts_k<<<(N_ATOMS + 255) / 256, blk, 0, stream>>>(mol_ids, cnt);
    scatter_k<<<(N_ATOMS * QH + 255) / 256, blk, 0, stream>>>(P, mol_ids, out);
    divide_k<<<(NMOL * H + 255) / 256, blk, 0, stream>>>(out, cnt);
}

// Round 5
// 1566.154 us; speedup vs baseline: 2.9359x; 1.2427x over previous
//
#include <hip/hip_runtime.h>

// ---- problem constants ----
constexpr int N_ATOMS = 100000;
constexpr int NATOMS1 = 100001;
constexpr int NBONDS1 = 200001;
constexpr int MAXNB   = 6;
constexpr int AF      = 133;    // ATOM_FDIM
constexpr int BF      = 147;    // BOND_FDIM
constexpr int H       = 300;    // HIDDEN
constexpr int NMOL    = 2048;
constexpr int KP      = 448;    // padded K for both GEMM families
constexpr int NP      = 320;    // padded N (20 frags of 16)
constexpr int QCOL_B  = 148;    // bond-msg column offset in AB (148*2=296 B, 8B-aligned)
constexpr int QCOL_A  = 136;    // a_msg column offset in AA    (136*2=272 B, 8B-aligned)
constexpr int QH      = 75;     // 300/4 groups per row

typedef unsigned short u16;
typedef unsigned int   u32;
typedef __attribute__((ext_vector_type(8))) short bh8;   // 8 bf16 = 4 VGPRs
typedef __attribute__((ext_vector_type(4))) float f32x4;

__device__ inline float b2f(u16 h) {
    union { u32 u; float f; } x; x.u = ((u32)h) << 16; return x.f;
}
__device__ inline u16 f2b(float f) {
    union { float f; u32 u; } x; x.f = f;
    return (u16)((x.u + 0x7FFFu + ((x.u >> 16) & 1u)) >> 16);
}

// =====================  MFMA GEMM  =====================
// out[M x 300] = relu( A[M x 448](bf16) @ Wt^T + bias? )
// Wt is [320 x 448] bf16 (column c of W stored as row c), zero-padded.
// Block: 256 thr = 4 waves; tile 64 rows x 320 cols (wave w: cols 80w..80w+79).
template<bool HAS_BIAS>
__global__ __launch_bounds__(256, 2)
void mfma_gemm_k(const u16* __restrict__ A, const u16* __restrict__ Wt,
                 const float* __restrict__ bias, u16* __restrict__ out, int M)
{
    __shared__ __align__(16) unsigned char smem[48 * 1024];  // A: 8KB, B: 40KB
    const int tid  = threadIdx.x;
    const int lane = tid & 63;
    const int w    = tid >> 6;
    const int row0 = blockIdx.x * 64;

    f32x4 acc[4][5];
    #pragma unroll
    for (int i = 0; i < 4; ++i)
        #pragma unroll
        for (int j = 0; j < 5; ++j)
            acc[i][j] = (f32x4)0.f;

    for (int kt = 0; kt < KP / 64; ++kt) {
        const int k0 = kt * 64;
        // ---- stage A tile (64 x 64 bf16 = 8KB), fragment order ----
        #pragma unroll
        for (int i = 0; i < 2; ++i) {
            int cid = tid + 256 * i;
            int r   = cid & 63;
            int kk  = cid >> 6;           // 0..7 (8-bf16 chunk)
            int ks  = kk >> 2, sub = kk & 3;
            uint4 v = {0u, 0u, 0u, 0u};
            int row = row0 + r;
            if (row < M) v = *(const uint4*)(A + (size_t)row * KP + k0 + kk * 8);
            *(uint4*)(smem + (((r >> 4) * 2 + ks) * 1024) + sub * 256 + (r & 15) * 16) = v;
        }
        // ---- stage B tile (320 cols x 64 k = 40KB), fragment order ----
        #pragma unroll
        for (int i = 0; i < 10; ++i) {
            int cid = tid + 256 * i;      // 0..2559
            int kk  = cid / 320;
            int col = cid - kk * 320;
            int ks  = kk >> 2, sub = kk & 3;
            uint4 v = *(const uint4*)(Wt + (size_t)col * KP + k0 + kk * 8);
            *(uint4*)(smem + 8192 + (((col >> 4) * 2 + ks) * 1024) + sub * 256 + (col & 15) * 16) = v;
        }
        __syncthreads();
        #pragma unroll
        for (int ks = 0; ks < 2; ++ks) {
            bh8 af[4], bf_[5];
            #pragma unroll
            for (int fm = 0; fm < 4; ++fm)
                af[fm] = *(const bh8*)(smem + (fm * 2 + ks) * 1024 + lane * 16);
            #pragma unroll
            for (int cf = 0; cf < 5; ++cf)
                bf_[cf] = *(const bh8*)(smem + 8192 + ((w * 5 + cf) * 2 + ks) * 1024 + lane * 16);
            #pragma unroll
            for (int fm = 0; fm < 4; ++fm)
                #pragma unroll
                for (int cf = 0; cf < 5; ++cf)
                    acc[fm][cf] = __builtin_amdgcn_mfma_f32_16x16x32_bf16(
                        af[fm], bf_[cf], acc[fm][cf], 0, 0, 0);
        }
        __syncthreads();
    }

    // epilogue: D row = (lane>>4)*4 + i (+16*fm), col = lane&15 (+16*cf +80*w)
    const int r4  = (lane >> 4) * 4;
    const int c15 = lane & 15;
    #pragma unroll
    for (int cf = 0; cf < 5; ++cf) {
        int col = w * 80 + cf * 16 + c15;
        if (col >= H) continue;
        float bv = HAS_BIAS ? bias[col] : 0.f;
        #pragma unroll
        for (int fm = 0; fm < 4; ++fm) {
            #pragma unroll
            for (int i = 0; i < 4; ++i) {
                int row = row0 + fm * 16 + r4 + i;
                if (row < M)
                    out[(size_t)row * H + col] = f2b(fmaxf(acc[fm][cf][i] + bv, 0.f));
            }
        }
    }
}

// =====================  prep kernels  =====================
__global__ __launch_bounds__(256)
void prep_w_k(const float* __restrict__ Wi, const float* __restrict__ Wh,
              const float* __restrict__ Wo, u16* __restrict__ Wtih, u16* __restrict__ Wto)
{
    int c = blockIdx.x;              // 0..319
    for (int k = threadIdx.x; k < KP; k += 256) {
        u16 v1 = 0, v2 = 0;
        if (c < H) {
            if (k < BF)              v1 = f2b(Wi[k * H + c]);
            else if (k >= QCOL_B)    v1 = f2b(Wh[(k - QCOL_B) * H + c]);
            if (k < AF)              v2 = f2b(Wo[k * H + c]);
            else if (k >= QCOL_A && k < QCOL_A + H)
                                     v2 = f2b(Wo[(AF + k - QCOL_A) * H + c]);
        }
        Wtih[c * KP + k] = v1;
        Wto[c * KP + k]  = v2;
    }
}

__global__ __launch_bounds__(256)
void prep_bonds_k(const float* __restrict__ fb, u16* __restrict__ AB)
{
    int idx = blockIdx.x * 256 + threadIdx.x;
    if (idx >= NBONDS1 * (KP / 4)) return;
    int b = idx / (KP / 4), g = idx - b * (KP / 4);
    int c0 = g * 4;
    u16 o[4];
    #pragma unroll
    for (int j = 0; j < 4; ++j) {
        int c = c0 + j;
        o[j] = (c < BF) ? f2b(fb[(size_t)b * BF + c]) : (u16)0;
    }
    uint2 p;
    p.x = (u32)o[0] | ((u32)o[1] << 16);
    p.y = (u32)o[2] | ((u32)o[3] << 16);
    *(uint2*)(AB + (size_t)b * KP + c0) = p;
}

__global__ __launch_bounds__(256)
void prep_atoms_k(const float* __restrict__ fa, u16* __restrict__ AA)
{
    int idx = blockIdx.x * 256 + threadIdx.x;   // NATOMS1 * 37 groups
    if (idx >= NATOMS1 * 37) return;
    int a = idx / 37, g = idx - a * 37;
    int c0 = (g < 34) ? g * 4 : 436 + (g - 34) * 4;
    u16 o[4];
    #pragma unroll
    for (int j = 0; j < 4; ++j) {
        int c = c0 + j;
        o[j] = (c < AF) ? f2b(fa[(size_t)a * AF + c]) : (u16)0;
    }
    uint2 p;
    p.x = (u32)o[0] | ((u32)o[1] << 16);
    p.y = (u32)o[2] | ((u32)o[3] << 16);
    *(uint2*)(AA + (size_t)a * KP + c0) = p;
}

// =====================  gather kernels  =====================
__global__ __launch_bounds__(256)
void atom_sum_k(const u16* __restrict__ P, const int* __restrict__ a2b,
                u16* __restrict__ AA)
{
    int idx = blockIdx.x * 256 + threadIdx.x;
    if (idx >= NATOMS1 * QH) return;
    int a = idx / QH, q = idx - a * QH;
    const int* nb = a2b + a * MAXNB;
    float s0 = 0.f, s1 = 0.f, s2 = 0.f, s3 = 0.f;
    #pragma unroll
    for (int j = 0; j < MAXNB; ++j) {
        int b = nb[j];
        uint2 v = *(const uint2*)(P + (size_t)b * H + q * 4);
        s0 += b2f((u16)(v.x & 0xFFFF)); s1 += b2f((u16)(v.x >> 16));
        s2 += b2f((u16)(v.y & 0xFFFF)); s3 += b2f((u16)(v.y >> 16));
    }
    uint2 o;
    o.x = (u32)f2b(s0) | ((u32)f2b(s1) << 16);
    o.y = (u32)f2b(s2) | ((u32)f2b(s3) << 16);
    *(uint2*)(AA + (size_t)a * KP + QCOL_A + q * 4) = o;
}

__global__ __launch_bounds__(256)
void bond_update_k(const u16* __restrict__ AA, const u16* __restrict__ P,
                   const int* __restrict__ b2a, const int* __restrict__ b2revb,
                   u16* __restrict__ AB)
{
    int idx = blockIdx.x * 256 + threadIdx.x;
    if (idx >= NBONDS1 * QH) return;
    int b = idx / QH, q = idx - b * QH;
    int a  = b2a[b];
    int rb = b2revb[b];
    uint2 x = *(const uint2*)(AA + (size_t)a * KP + QCOL_A + q * 4);
    uint2 y = *(const uint2*)(P + (size_t)rb * H + q * 4);
    float v0 = b2f((u16)(x.x & 0xFFFF)) - b2f((u16)(y.x & 0xFFFF));
    float v1 = b2f((u16)(x.x >> 16))    - b2f((u16)(y.x >> 16));
    float v2 = b2f((u16)(x.y & 0xFFFF)) - b2f((u16)(y.y & 0xFFFF));
    float v3 = b2f((u16)(x.y >> 16))    - b2f((u16)(y.y >> 16));
    uint2 o;
    o.x = (u32)f2b(v0) | ((u32)f2b(v1) << 16);
    o.y = (u32)f2b(v2) | ((u32)f2b(v3) << 16);
    *(uint2*)(AB + (size_t)b * KP + QCOL_B + q * 4) = o;
}

// =====================  mol pooling (bucketed, no fp32 atomics)  =====================
__global__ __launch_bounds__(256)
void hist_k(const int* __restrict__ mol_ids, int* __restrict__ cnt)
{
    int i = blockIdx.x * 256 + threadIdx.x;
    if (i < N_ATOMS) atomicAdd(&cnt[mol_ids[i]], 1);
}

// exclusive scan of cnt[0..2047] -> offs ; single block of 256 threads, 8 elems each
__global__ __launch_bounds__(256)
void scan_k(const int* __restrict__ cnt, int* __restrict__ offs)
{
    __shared__ int lds[256];
    const int t = threadIdx.x;
    int v[8];
    int s = 0;
    #pragma unroll
    for (int j = 0; j < 8; ++j) { v[j] = cnt[t * 8 + j]; s += v[j]; }
    lds[t] = s;
    __syncthreads();
    int run = s;
    #pragma unroll
    for (int d = 1; d < 256; d <<= 1) {
        int add = (t >= d) ? lds[t - d] : 0;
        __syncthreads();
        lds[t] += add;
        __syncthreads();
    }
    int excl = lds[t] - run;           // exclusive prefix of this thread's chunk
    #pragma unroll
    for (int j = 0; j < 8; ++j) { offs[t * 8 + j] = excl; excl += v[j]; }
}

__global__ __launch_bounds__(256)
void fill_k(const int* __restrict__ mol_ids, const int* __restrict__ offs,
            int* __restrict__ fill, int* __restrict__ bucket)
{
    int i = blockIdx.x * 256 + threadIdx.x;
    if (i >= N_ATOMS) return;
    int m = mol_ids[i];
    int pos = offs[m] + atomicAdd(&fill[m], 1);
    bucket[pos] = i;
}

// one block per mol: thread c sums column c over the mol's atoms, writes mean
__global__ __launch_bounds__(320)
void mol_sum_k(const u16* __restrict__ ah, const int* __restrict__ offs,
               const int* __restrict__ cnt, const int* __restrict__ bucket,
               float* __restrict__ out)
{
    const int m = blockIdx.x;
    const int c = threadIdx.x;
    if (c >= H) return;
    const int start = offs[m];
    const int n     = cnt[m];
    float s = 0.f;
    for (int j = 0; j < n; ++j) {
        int a = bucket[start + j];
        s += b2f(ah[(size_t)(a + 1) * H + c]);
    }
    out[(size_t)m * H + c] = s / fmaxf((float)n, 1.0f);
}

// =====================  driver  =====================
extern "C" void kernel_launch(void* const* d_in, const int* in_sizes, int n_in,
                              void* d_out, int out_size, void* d_ws, size_t ws_size,
                              hipStream_t stream)
{
    const float* f_atoms = (const float*)d_in[0];
    const float* f_bonds = (const float*)d_in[1];
    const float* W_i     = (const float*)d_in[2];
    const float* W_h     = (const float*)d_in[3];
    const float* W_o     = (const float*)d_in[4];
    const float* b_o     = (const float*)d_in[5];
    const int*   a2b     = (const int*)d_in[6];
    const int*   b2a     = (const int*)d_in[7];
    const int*   b2revb  = (const int*)d_in[8];
    const int*   mol_ids = (const int*)d_in[9];
    float* out = (float*)d_out;

    char* ws = (char*)d_ws;
    size_t off = 0;
    auto alloc = [&](size_t bytes) -> void* {
        void* p = ws + off;
        off += (bytes + 255) & ~(size_t)255;
        return p;
    };
    u16* AB    = (u16*)alloc(sizeof(u16) * (size_t)NBONDS1 * KP);  // 179.2 MB
    u16* AA    = (u16*)alloc(sizeof(u16) * (size_t)NATOMS1 * KP);  //  89.6 MB
    u16* P     = (u16*)alloc(sizeof(u16) * (size_t)NBONDS1 * H);   // 120.0 MB (bond msgs / atom_hiddens)
    u16* Wtih  = (u16*)alloc(sizeof(u16) * (size_t)NP * KP);       // 287 KB
    u16* Wto   = (u16*)alloc(sizeof(u16) * (size_t)NP * KP);       // 287 KB
    int* cnt    = (int*)alloc(sizeof(int) * NMOL);
    int* offs   = (int*)alloc(sizeof(int) * NMOL);
    int* fill   = (int*)alloc(sizeof(int) * NMOL);
    int* bucket = (int*)alloc(sizeof(int) * N_ATOMS);
    const size_t needed = off;                                     // ~389.8 MB

    if (ws_size < needed) {
        // Diagnostic: absmax exactly 28.625 (zeros) => ws too small.
        hipMemsetAsync(d_out, 0, sizeof(float) * (size_t)NMOL * H, stream);
        return;
    }

    hipMemsetAsync(cnt, 0, sizeof(int) * NMOL, stream);
    hipMemsetAsync(fill, 0, sizeof(int) * NMOL, stream);

    const dim3 blk(256);
    const int gB  = (NBONDS1 + 63) / 64;                 // 3126
    const int gA  = (NATOMS1 + 63) / 64;                 // 1563
    const int gAS = (NATOMS1 * QH + 255) / 256;
    const int gBU = (NBONDS1 * QH + 255) / 256;

    prep_w_k<<<NP, blk, 0, stream>>>(W_i, W_h, W_o, Wtih, Wto);
    prep_bonds_k<<<(NBONDS1 * (KP / 4) + 255) / 256, blk, 0, stream>>>(f_bonds, AB);
    prep_atoms_k<<<(NATOMS1 * 37 + 255) / 256, blk, 0, stream>>>(f_atoms, AA);

    // layer 1: bond-msg region of AB is zero -> AB@[Wi;Wh] == f_bonds@W_i
    mfma_gemm_k<false><<<gB, blk, 0, stream>>>(AB, Wtih, nullptr, P, NBONDS1);

    for (int d = 0; d < 2; ++d) {
        atom_sum_k<<<gAS, blk, 0, stream>>>(P, a2b, AA);
        bond_update_k<<<gBU, blk, 0, stream>>>(AA, P, b2a, b2revb, AB);
        mfma_gemm_k<false><<<gB, blk, 0, stream>>>(AB, Wtih, nullptr, P, NBONDS1);
    }
    atom_sum_k<<<gAS, blk, 0, stream>>>(P, a2b, AA);

    // atom layer: reuse P as atom_hiddens
    mfma_gemm_k<true><<<gA, blk, 0, stream>>>(AA, Wto, b_o, P, NATOMS1);

    // bucketed mol mean (no fp32 atomics)
    hist_k<<<(N_ATOMS + 255) / 256, blk, 0, stream>>>(mol_ids, cnt);
    scan_k<<<1, blk, 0, stream>>>(cnt, offs);
    fill_k<<<(N_ATOMS + 255) / 256, blk, 0, stream>>>(mol_ids, offs, fill, bucket);
    mol_sum_k<<<NMOL, dim3(320), 0, stream>>>(P, offs, cnt, bucket, out);
}

// Round 6
// 1425.084 us; speedup vs baseline: 3.2265x; 1.0990x over previous
//
#include <hip/hip_runtime.h>

// ---- problem constants ----
constexpr int N_ATOMS = 100000;
constexpr int NATOMS1 = 100001;
constexpr int NBONDS1 = 200001;
constexpr int MAXNB   = 6;
constexpr int AF      = 133;    // ATOM_FDIM
constexpr int BF      = 147;    // BOND_FDIM
constexpr int H       = 300;    // HIDDEN
constexpr int NMOL    = 2048;
constexpr int KP      = 448;    // padded K for both GEMM families
constexpr int NP      = 320;    // padded N (20 frags of 16)
constexpr int QCOL_B  = 148;    // bond-msg column offset in AB (8B-aligned)
constexpr int QCOL_A  = 136;    // a_msg column offset in AA    (8B-aligned)
constexpr int QH      = 75;     // 300/4 groups per row
constexpr int NBP     = ((NBONDS1 + 63) / 64) * 64;   // 200064 (padded rows)
constexpr int NAP     = ((NATOMS1 + 63) / 64) * 64;   // 100032

typedef unsigned short u16;
typedef unsigned int   u32;
typedef __attribute__((ext_vector_type(8))) short bh8;   // 8 bf16 = 4 VGPRs
typedef __attribute__((ext_vector_type(4))) float f32x4;

__device__ inline float b2f(u16 h) {
    union { u32 u; float f; } x; x.u = ((u32)h) << 16; return x.f;
}
__device__ inline u16 f2b(float f) {
    union { float f; u32 u; } x; x.f = f;
    return (u16)((x.u + 0x7FFFu + ((x.u >> 16) & 1u)) >> 16);
}

__device__ __forceinline__ void gld_lds16(const u16* g, unsigned char* l)
{
    __builtin_amdgcn_global_load_lds(
        (const __attribute__((address_space(1))) unsigned int*)g,
        (__attribute__((address_space(3))) unsigned int*)l,
        16, 0, 0);
}

// =====================  MFMA GEMM  =====================
// out[M x 300] = relu( A[M x 448](bf16) @ Wt^T + bias? )
// Wt: [320 x 448] bf16 (col c of W as row c), zero-padded.
// Block: 320 thr = 5 waves; tile 64 rows x 320 cols; BK=32 (one MFMA K-step).
// LDS 24KB: A regions fm=0..3 at fm*1024; B regions cb=0..19 at 4096+cb*1024.
// Region = 1024B: lane l holds [16-row block row=(l&15)][k-chunk (l>>4)*8 ..+8].
// Staged via global_load_lds: lds dst = region_base + lane*16 (linear), source
// address per-lane (pre-swizzled) -> fragment-order LDS with zero VGPR staging.
template<bool HAS_BIAS>
__global__ __launch_bounds__(320, 4)
void mfma_gemm_k(const u16* __restrict__ A, const u16* __restrict__ Wt,
                 const float* __restrict__ bias, u16* __restrict__ out, int M)
{
    __shared__ __align__(16) unsigned char smem[24 * 1024];
    const int tid  = threadIdx.x;
    const int lane = tid & 63;
    const int w    = tid >> 6;          // 0..4
    const int row0 = blockIdx.x * 64;

    // per-lane staging jobs: job j of wave w -> region r = w*5+j (r<24)
    const u16* src[5];
    unsigned char* dst[5];
    #pragma unroll
    for (int j = 0; j < 5; ++j) {
        int r = w * 5 + j;
        if (r < 4) {            // A region rblk=r
            src[j] = A + (size_t)(row0 + r * 16 + (lane & 15)) * KP + (lane >> 4) * 8;
            dst[j] = smem + r * 1024 + lane * 16;
        } else if (r < 24) {    // B region cb=r-4
            int cb = r - 4;
            src[j] = Wt + (size_t)(cb * 16 + (lane & 15)) * KP + (lane >> 4) * 8;
            dst[j] = smem + 4096 + cb * 1024 + lane * 16;
        } else {
            src[j] = nullptr; dst[j] = nullptr;
        }
    }
    const int njobs = (w == 4) ? 4 : 5;

    f32x4 acc[4][4];
    #pragma unroll
    for (int i = 0; i < 4; ++i)
        #pragma unroll
        for (int j = 0; j < 4; ++j)
            acc[i][j] = (f32x4)0.f;

    for (int kt = 0; kt < KP / 32; ++kt) {
        #pragma unroll
        for (int j = 0; j < 5; ++j)
            if (j < njobs) gld_lds16(src[j] + kt * 32, dst[j]);
        __syncthreads();
        bh8 af[4], bfr[4];
        #pragma unroll
        for (int fm = 0; fm < 4; ++fm)
            af[fm] = *(const bh8*)(smem + fm * 1024 + lane * 16);
        #pragma unroll
        for (int cf = 0; cf < 4; ++cf)
            bfr[cf] = *(const bh8*)(smem + 4096 + (w * 4 + cf) * 1024 + lane * 16);
        #pragma unroll
        for (int fm = 0; fm < 4; ++fm)
            #pragma unroll
            for (int cf = 0; cf < 4; ++cf)
                acc[fm][cf] = __builtin_amdgcn_mfma_f32_16x16x32_bf16(
                    af[fm], bfr[cf], acc[fm][cf], 0, 0, 0);
        __syncthreads();
    }

    // epilogue: D row = (lane>>4)*4 + i (+16*fm), col = (lane&15) +16*cf +64*w
    const int r4  = (lane >> 4) * 4;
    const int c15 = lane & 15;
    #pragma unroll
    for (int cf = 0; cf < 4; ++cf) {
        int col = w * 64 + cf * 16 + c15;
        if (col >= H) continue;
        float bv = HAS_BIAS ? bias[col] : 0.f;
        #pragma unroll
        for (int fm = 0; fm < 4; ++fm) {
            #pragma unroll
            for (int i = 0; i < 4; ++i) {
                int row = row0 + fm * 16 + r4 + i;
                if (row < M)
                    out[(size_t)row * H + col] = f2b(fmaxf(acc[fm][cf][i] + bv, 0.f));
            }
        }
    }
}

// =====================  prep kernels  =====================
__global__ __launch_bounds__(256)
void prep_w_k(const float* __restrict__ Wi, const float* __restrict__ Wh,
              const float* __restrict__ Wo, u16* __restrict__ Wtih, u16* __restrict__ Wto)
{
    int c = blockIdx.x;              // 0..319
    for (int k = threadIdx.x; k < KP; k += 256) {
        u16 v1 = 0, v2 = 0;
        if (c < H) {
            if (k < BF)              v1 = f2b(Wi[k * H + c]);
            else if (k >= QCOL_B)    v1 = f2b(Wh[(k - QCOL_B) * H + c]);
            if (k < AF)              v2 = f2b(Wo[k * H + c]);
            else if (k >= QCOL_A && k < QCOL_A + H)
                                     v2 = f2b(Wo[(AF + k - QCOL_A) * H + c]);
        }
        Wtih[c * KP + k] = v1;
        Wto[c * KP + k]  = v2;
    }
}

__global__ __launch_bounds__(256)
void prep_bonds_k(const float* __restrict__ fb, u16* __restrict__ AB)
{
    int idx = blockIdx.x * 256 + threadIdx.x;
    if (idx >= NBONDS1 * (KP / 4)) return;
    int b = idx / (KP / 4), g = idx - b * (KP / 4);
    int c0 = g * 4;
    u16 o[4];
    #pragma unroll
    for (int j = 0; j < 4; ++j) {
        int c = c0 + j;
        o[j] = (c < BF) ? f2b(fb[(size_t)b * BF + c]) : (u16)0;
    }
    uint2 p;
    p.x = (u32)o[0] | ((u32)o[1] << 16);
    p.y = (u32)o[2] | ((u32)o[3] << 16);
    *(uint2*)(AB + (size_t)b * KP + c0) = p;
}

__global__ __launch_bounds__(256)
void prep_atoms_k(const float* __restrict__ fa, u16* __restrict__ AA)
{
    int idx = blockIdx.x * 256 + threadIdx.x;   // NATOMS1 * 37 groups
    if (idx >= NATOMS1 * 37) return;
    int a = idx / 37, g = idx - a * 37;
    int c0 = (g < 34) ? g * 4 : 436 + (g - 34) * 4;
    u16 o[4];
    #pragma unroll
    for (int j = 0; j < 4; ++j) {
        int c = c0 + j;
        o[j] = (c < AF) ? f2b(fa[(size_t)a * AF + c]) : (u16)0;
    }
    uint2 p;
    p.x = (u32)o[0] | ((u32)o[1] << 16);
    p.y = (u32)o[2] | ((u32)o[3] << 16);
    *(uint2*)(AA + (size_t)a * KP + c0) = p;
}

// =====================  gather kernels  =====================
__global__ __launch_bounds__(256)
void atom_sum_k(const u16* __restrict__ P, const int* __restrict__ a2b,
                u16* __restrict__ AA)
{
    int idx = blockIdx.x * 256 + threadIdx.x;
    if (idx >= NATOMS1 * QH) return;
    int a = idx / QH, q = idx - a * QH;
    const int* nb = a2b + a * MAXNB;
    float s0 = 0.f, s1 = 0.f, s2 = 0.f, s3 = 0.f;
    #pragma unroll
    for (int j = 0; j < MAXNB; ++j) {
        int b = nb[j];
        uint2 v = *(const uint2*)(P + (size_t)b * H + q * 4);
        s0 += b2f((u16)(v.x & 0xFFFF)); s1 += b2f((u16)(v.x >> 16));
        s2 += b2f((u16)(v.y & 0xFFFF)); s3 += b2f((u16)(v.y >> 16));
    }
    uint2 o;
    o.x = (u32)f2b(s0) | ((u32)f2b(s1) << 16);
    o.y = (u32)f2b(s2) | ((u32)f2b(s3) << 16);
    *(uint2*)(AA + (size_t)a * KP + QCOL_A + q * 4) = o;
}

__global__ __launch_bounds__(256)
void bond_update_k(const u16* __restrict__ AA, const u16* __restrict__ P,
                   const int* __restrict__ b2a, const int* __restrict__ b2revb,
                   u16* __restrict__ AB)
{
    int idx = blockIdx.x * 256 + threadIdx.x;
    if (idx >= NBONDS1 * QH) return;
    int b = idx / QH, q = idx - b * QH;
    int a  = b2a[b];
    int rb = b2revb[b];
    uint2 x = *(const uint2*)(AA + (size_t)a * KP + QCOL_A + q * 4);
    uint2 y = *(const uint2*)(P + (size_t)rb * H + q * 4);
    float v0 = b2f((u16)(x.x & 0xFFFF)) - b2f((u16)(y.x & 0xFFFF));
    float v1 = b2f((u16)(x.x >> 16))    - b2f((u16)(y.x >> 16));
    float v2 = b2f((u16)(x.y & 0xFFFF)) - b2f((u16)(y.y & 0xFFFF));
    float v3 = b2f((u16)(x.y >> 16))    - b2f((u16)(y.y >> 16));
    uint2 o;
    o.x = (u32)f2b(v0) | ((u32)f2b(v1) << 16);
    o.y = (u32)f2b(v2) | ((u32)f2b(v3) << 16);
    *(uint2*)(AB + (size_t)b * KP + QCOL_B + q * 4) = o;
}

// =====================  mol pooling (bucketed, no fp32 atomics)  =====================
__global__ __launch_bounds__(256)
void hist_k(const int* __restrict__ mol_ids, int* __restrict__ cnt)
{
    int i = blockIdx.x * 256 + threadIdx.x;
    if (i < N_ATOMS) atomicAdd(&cnt[mol_ids[i]], 1);
}

__global__ __launch_bounds__(256)
void scan_k(const int* __restrict__ cnt, int* __restrict__ offs)
{
    __shared__ int lds[256];
    const int t = threadIdx.x;
    int v[8];
    int s = 0;
    #pragma unroll
    for (int j = 0; j < 8; ++j) { v[j] = cnt[t * 8 + j]; s += v[j]; }
    lds[t] = s;
    __syncthreads();
    int run = s;
    #pragma unroll
    for (int d = 1; d < 256; d <<= 1) {
        int add = (t >= d) ? lds[t - d] : 0;
        __syncthreads();
        lds[t] += add;
        __syncthreads();
    }
    int excl = lds[t] - run;
    #pragma unroll
    for (int j = 0; j < 8; ++j) { offs[t * 8 + j] = excl; excl += v[j]; }
}

__global__ __launch_bounds__(256)
void fill_k(const int* __restrict__ mol_ids, const int* __restrict__ offs,
            int* __restrict__ fill, int* __restrict__ bucket)
{
    int i = blockIdx.x * 256 + threadIdx.x;
    if (i >= N_ATOMS) return;
    int m = mol_ids[i];
    int pos = offs[m] + atomicAdd(&fill[m], 1);
    bucket[pos] = i;
}

__global__ __launch_bounds__(320)
void mol_sum_k(const u16* __restrict__ ah, const int* __restrict__ offs,
               const int* __restrict__ cnt, const int* __restrict__ bucket,
               float* __restrict__ out)
{
    const int m = blockIdx.x;
    const int c = threadIdx.x;
    if (c >= H) return;
    const int start = offs[m];
    const int n     = cnt[m];
    float s = 0.f;
    for (int j = 0; j < n; ++j) {
        int a = bucket[start + j];
        s += b2f(ah[(size_t)(a + 1) * H + c]);
    }
    out[(size_t)m * H + c] = s / fmaxf((float)n, 1.0f);
}

// =====================  driver  =====================
extern "C" void kernel_launch(void* const* d_in, const int* in_sizes, int n_in,
                              void* d_out, int out_size, void* d_ws, size_t ws_size,
                              hipStream_t stream)
{
    const float* f_atoms = (const float*)d_in[0];
    const float* f_bonds = (const float*)d_in[1];
    const float* W_i     = (const float*)d_in[2];
    const float* W_h     = (const float*)d_in[3];
    const float* W_o     = (const float*)d_in[4];
    const float* b_o     = (const float*)d_in[5];
    const int*   a2b     = (const int*)d_in[6];
    const int*   b2a     = (const int*)d_in[7];
    const int*   b2revb  = (const int*)d_in[8];
    const int*   mol_ids = (const int*)d_in[9];
    float* out = (float*)d_out;

    char* ws = (char*)d_ws;
    size_t off = 0;
    auto alloc = [&](size_t bytes) -> void* {
        void* p = ws + off;
        off += (bytes + 255) & ~(size_t)255;
        return p;
    };
    u16* AB    = (u16*)alloc(sizeof(u16) * (size_t)NBP * KP);      // 179.3 MB (row-padded)
    u16* AA    = (u16*)alloc(sizeof(u16) * (size_t)NAP * KP);      //  89.6 MB (row-padded)
    u16* P     = (u16*)alloc(sizeof(u16) * (size_t)NBONDS1 * H);   // 120.0 MB
    u16* Wtih  = (u16*)alloc(sizeof(u16) * (size_t)NP * KP);       // 287 KB
    u16* Wto   = (u16*)alloc(sizeof(u16) * (size_t)NP * KP);       // 287 KB
    int* cnt    = (int*)alloc(sizeof(int) * NMOL);
    int* offs   = (int*)alloc(sizeof(int) * NMOL);
    int* fill   = (int*)alloc(sizeof(int) * NMOL);
    int* bucket = (int*)alloc(sizeof(int) * N_ATOMS);
    const size_t needed = off;                                     // ~390 MB

    if (ws_size < needed) {
        // Diagnostic: absmax exactly 28.625 (zeros) => ws too small.
        hipMemsetAsync(d_out, 0, sizeof(float) * (size_t)NMOL * H, stream);
        return;
    }

    hipMemsetAsync(cnt, 0, sizeof(int) * NMOL, stream);
    hipMemsetAsync(fill, 0, sizeof(int) * NMOL, stream);

    const dim3 blk(256);
    const dim3 gblk(320);
    const int gB  = NBP / 64;                            // 3126
    const int gA  = NAP / 64;                            // 1563
    const int gAS = (NATOMS1 * QH + 255) / 256;
    const int gBU = (NBONDS1 * QH + 255) / 256;

    prep_w_k<<<NP, blk, 0, stream>>>(W_i, W_h, W_o, Wtih, Wto);
    prep_bonds_k<<<(NBONDS1 * (KP / 4) + 255) / 256, blk, 0, stream>>>(f_bonds, AB);
    prep_atoms_k<<<(NATOMS1 * 37 + 255) / 256, blk, 0, stream>>>(f_atoms, AA);

    // layer 1: bond-msg region of AB is zero -> AB@[Wi;Wh] == f_bonds@W_i
    mfma_gemm_k<false><<<gB, gblk, 0, stream>>>(AB, Wtih, nullptr, P, NBONDS1);

    for (int d = 0; d < 2; ++d) {
        atom_sum_k<<<gAS, blk, 0, stream>>>(P, a2b, AA);
        bond_update_k<<<gBU, blk, 0, stream>>>(AA, P, b2a, b2revb, AB);
        mfma_gemm_k<false><<<gB, gblk, 0, stream>>>(AB, Wtih, nullptr, P, NBONDS1);
    }
    atom_sum_k<<<gAS, blk, 0, stream>>>(P, a2b, AA);

    // atom layer: reuse P as atom_hiddens
    mfma_gemm_k<true><<<gA, gblk, 0, stream>>>(AA, Wto, b_o, P, NATOMS1);

    // bucketed mol mean (no fp32 atomics)
    hist_k<<<(N_ATOMS + 255) / 256, blk, 0, stream>>>(mol_ids, cnt);
    scan_k<<<1, blk, 0, stream>>>(cnt, offs);
    fill_k<<<(N_ATOMS + 255) / 256, blk, 0, stream>>>(mol_ids, offs, fill, bucket);
    mol_sum_k<<<NMOL, gblk, 0, stream>>>(P, offs, cnt, bucket, out);
}